// Round 17
// baseline (318.794 us; speedup 1.0000x reference)
//
#include <hip/hip_runtime.h>
#include <stdint.h>

#define N_NODES 50000
#define N_EDGES 800000
#define HID 128
#define NWG_E (N_EDGES / 128)      // 6250 edge blocks
#define XQ (NWG_E / 8)             // 781
#define XR (NWG_E % 8)             // 2
#define SCAN_B 196                 // 196*256 = 50176 >= N_NODES
#define DMAX 24                    // max dst-range per block for LDS-table path

#define ENC_NEG_INF 0x007FFFFFu   // enc(-inf)

typedef short short8 __attribute__((ext_vector_type(8)));
typedef float f32x4 __attribute__((ext_vector_type(4)));
typedef unsigned int uint32x4 __attribute__((ext_vector_type(4)));

__device__ __forceinline__ unsigned enc_f32(float f) {
    unsigned u = __float_as_uint(f);
    return (u & 0x80000000u) ? ~u : (u | 0x80000000u);
}
__device__ __forceinline__ float dec_f32(unsigned e) {
    unsigned u = (e & 0x80000000u) ? (e & 0x7FFFFFFFu) : ~e;
    return __uint_as_float(u);
}
__device__ __forceinline__ unsigned short f2bf(float f) {   // RNE bit-trick
    unsigned u = __float_as_uint(f);
    unsigned r = (u + 0x7fffu + ((u >> 16) & 1u)) >> 16;
    return (unsigned short)r;
}
__device__ __forceinline__ float bf2f(unsigned short h) {
    return __uint_as_float(((unsigned)h) << 16);
}
// HW packed convert: 2 f32 -> bf16x2 word (RNE, v_cvt_pk_bf16_f32)
__device__ __forceinline__ unsigned cvt_pk_bf16(float lo, float hi) {
    unsigned r;
    asm("v_cvt_pk_bf16_f32 %0, %1, %2" : "=v"(r) : "v"(lo), "v"(hi));
    return r;
}
// t = relu(u + v) on a bf16x2 word, packed
__device__ __forceinline__ unsigned pack_relu_add(unsigned uu, unsigned vv) {
    float s0 = __uint_as_float(uu << 16) + __uint_as_float(vv << 16);
    float s1 = __uint_as_float(uu & 0xffff0000u) + __uint_as_float(vv & 0xffff0000u);
    return cvt_pk_bf16(fmaxf(s0, 0.f), fmaxf(s1, 0.f));
}
__device__ __forceinline__ float wcat_val(const float* __restrict__ W, int K, int k, int n) {
    return (n < 128) ? (W[k * 128 + n] - W[(k + K) * 128 + n]) : W[(k + K) * 128 + (n - 128)];
}

// run-aware reduce over 4 sorted edges -> LDS table (fast path).
// Common case (all 4 same dst): 1 compare + 1 atomic. Else: 4 plain atomics.
__device__ __forceinline__ void segmax4_l(int4 dd, f32x4 v, unsigned* AGGL, int dlo, int col) {
    if (dd.x == dd.w) {
        float mx = fmaxf(fmaxf(v[0], v[1]), fmaxf(v[2], v[3]));
        atomicMax(&AGGL[(dd.x - dlo) * 129 + col], enc_f32(mx));
    } else {
        atomicMax(&AGGL[(dd.x - dlo) * 129 + col], enc_f32(v[0]));
        atomicMax(&AGGL[(dd.y - dlo) * 129 + col], enc_f32(v[1]));
        atomicMax(&AGGL[(dd.z - dlo) * 129 + col], enc_f32(v[2]));
        atomicMax(&AGGL[(dd.w - dlo) * 129 + col], enc_f32(v[3]));
    }
}
// fallback: global atomics (rare; block-uniform)
__device__ __forceinline__ void segmax4_g(int4 dd, f32x4 v, unsigned* __restrict__ AGG, int col) {
    if (dd.x == dd.w) {
        float mx = fmaxf(fmaxf(v[0], v[1]), fmaxf(v[2], v[3]));
        atomicMax(&AGG[(size_t)dd.x * 128 + col], enc_f32(mx));
    } else {
        atomicMax(&AGG[(size_t)dd.x * 128 + col], enc_f32(v[0]));
        atomicMax(&AGG[(size_t)dd.y * 128 + col], enc_f32(v[1]));
        atomicMax(&AGG[(size_t)dd.z * 128 + col], enc_f32(v[2]));
        atomicMax(&AGG[(size_t)dd.w * 128 + col], enc_f32(v[3]));
    }
}

// ---------------- fused setup: W-frag preps (hi planes only) + big fills ----------------
__global__ __launch_bounds__(256) void setup(
        const float* __restrict__ W1a, const float* __restrict__ W1b,
        const float* __restrict__ W2a, const float* __restrict__ W2b,
        unsigned short* __restrict__ Wg1, unsigned short* __restrict__ Wg2,
        unsigned short* __restrict__ WCg1, unsigned short* __restrict__ WCg2,
        unsigned* __restrict__ AGG1, unsigned* __restrict__ OUT,
        unsigned* __restrict__ count) {
    int bid = blockIdx.x, tid = threadIdx.x;
    const int NH = N_NODES * HID;

    if (bid < 128) {
        const float* Wb = (bid < 64) ? W1b : W2b;
        unsigned short* Wg = (bid < 64) ? Wg1 : Wg2;
        int idx = (bid & 63) * 256 + tid;
        int j = idx & 7, l = (idx >> 3) & 63, t = idx >> 9;
        int h = t >> 4, kt = (t >> 2) & 3, ntl = t & 3;
        int nt = 4 * h + ntl;
        int k = 32 * kt + 8 * (l >> 4) + j;
        int n = 16 * nt + (l & 15);
        Wg[idx] = f2bf(Wb[k * 128 + n]);
    } else if (bid < 192) {
        int idx = (bid - 128) * 256 + tid;
        int j = idx & 7, l = (idx >> 3) & 63, nt = (idx >> 9) & 15, kt = idx >> 13;
        int k = 32 * kt + 8 * (l >> 4) + j;
        int n = 16 * nt + (l & 15);
        WCg1[idx] = f2bf(wcat_val(W1a, 64, k, n));
    } else if (bid < 320) {
        int idx = (bid - 192) * 256 + tid;
        int j = idx & 7, l = (idx >> 3) & 63, nt = (idx >> 9) & 15, kt = idx >> 13;
        int k = 32 * kt + 8 * (l >> 4) + j;
        int n = 16 * nt + (l & 15);
        WCg2[idx] = f2bf(wcat_val(W2a, 128, k, n));
    }

    int total = 2 * NH + N_NODES;
    for (int i = bid * 256 + tid; i < total; i += gridDim.x * 256) {
        if (i < NH) AGG1[i] = ENC_NEG_INF;
        else if (i < 2 * NH) OUT[i - NH] = ENC_NEG_INF;
        else count[i - 2 * NH] = 0u;
    }
}

__global__ void out_decode(unsigned* __restrict__ p, const float* __restrict__ bias, int n) {
    int i = blockIdx.x * blockDim.x + threadIdx.x;
    int stride = gridDim.x * blockDim.x;
    for (; i < n; i += stride) {
        unsigned e = p[i];
        float f = (e == ENC_NEG_INF) ? 0.0f : dec_f32(e) + bias[i & 127];
        ((float*)p)[i] = f;
    }
}

// ---------------- sort-by-dst (counting sort, multi-block scan) ----------------

__global__ void hist_dst(const int* __restrict__ dst, unsigned* __restrict__ count) {
    int i = blockIdx.x * blockDim.x + threadIdx.x;
    if (i < N_EDGES) atomicAdd(&count[dst[i]], 1u);
}

__global__ __launch_bounds__(256) void scan_p1(const unsigned* __restrict__ count,
                                               unsigned* __restrict__ bsum) {
    __shared__ unsigned s[256];
    int t = threadIdx.x;
    int i = blockIdx.x * 256 + t;
    s[t] = (i < N_NODES) ? count[i] : 0u;
    __syncthreads();
    for (int off = 128; off > 0; off >>= 1) {
        if (t < off) s[t] += s[t + off];
        __syncthreads();
    }
    if (t == 0) bsum[blockIdx.x] = s[0];
}

__global__ __launch_bounds__(256) void scan_p2(unsigned* __restrict__ bsum) {
    __shared__ unsigned s[256];
    int t = threadIdx.x;
    unsigned v = (t < SCAN_B) ? bsum[t] : 0u;
    s[t] = v;
    __syncthreads();
    for (int off = 1; off < 256; off <<= 1) {
        unsigned x = (t >= off) ? s[t - off] : 0u;
        __syncthreads();
        s[t] += x;
        __syncthreads();
    }
    if (t < SCAN_B) bsum[t] = s[t] - v;   // exclusive
}

__global__ __launch_bounds__(256) void scan_p3(const unsigned* __restrict__ count,
                                               const unsigned* __restrict__ bsum,
                                               unsigned* __restrict__ cursor) {
    __shared__ unsigned s[256];
    int t = threadIdx.x;
    int i = blockIdx.x * 256 + t;
    unsigned v = (i < N_NODES) ? count[i] : 0u;
    s[t] = v;
    __syncthreads();
    for (int off = 1; off < 256; off <<= 1) {
        unsigned x = (t >= off) ? s[t - off] : 0u;
        __syncthreads();
        s[t] += x;
        __syncthreads();
    }
    if (i < N_NODES) cursor[i] = bsum[blockIdx.x] + s[t] - v;
}

__global__ void scatter_edges(const int* __restrict__ src, const int* __restrict__ dst,
                              unsigned* __restrict__ cursor,
                              int* __restrict__ ssrc, int* __restrict__ sdst) {
    int i = blockIdx.x * blockDim.x + threadIdx.x;
    if (i < N_EDGES) {
        int d = dst[i];
        unsigned p = atomicAdd(&cursor[d], 1u);
        ssrc[p] = src[i];
        sdst[p] = d;
    }
}

// ---------------- MFMA node GEMM: C[M][256](bf16) = op(A)[M][K] @ WC_hi[K][256] ----------------
template<int DEC, int KT>
__global__ __launch_bounds__(256, 3) void gemm_uv_mfma(
        const void* __restrict__ A_,
        const unsigned short* __restrict__ Wg,
        const float* __restrict__ bprev,
        const float* __restrict__ bu,
        unsigned short* __restrict__ C,
        int M) {
    __shared__ char lds[KT * 8192];
    const int K = 32 * KT;
    int tid = threadIdx.x;
    int bx = blockIdx.x, by = blockIdx.y;
    int r0 = bx * 128;
    int w = tid >> 6, l = tid & 63;
    int q = l >> 4, m = l & 15;

    short8 ahi[2][KT];
#pragma unroll
    for (int mt = 0; mt < 2; ++mt) {
        int row = r0 + 32 * w + 16 * mt + m;
        bool ok = row < M;
#pragma unroll
        for (int kt = 0; kt < KT; ++kt) {
            float av[8] = {0.f, 0.f, 0.f, 0.f, 0.f, 0.f, 0.f, 0.f};
            if (ok) {
                if (DEC) {
                    const unsigned* Ar = (const unsigned*)A_ + (size_t)row * K + 32 * kt + 8 * q;
                    uint4 x0 = *(const uint4*)Ar;
                    uint4 x1 = *(const uint4*)(Ar + 4);
                    float4 g0 = *(const float4*)&bprev[32 * kt + 8 * q];
                    float4 g1 = *(const float4*)&bprev[32 * kt + 8 * q + 4];
                    av[0] = fmaxf(dec_f32(x0.x) + g0.x, 0.f);
                    av[1] = fmaxf(dec_f32(x0.y) + g0.y, 0.f);
                    av[2] = fmaxf(dec_f32(x0.z) + g0.z, 0.f);
                    av[3] = fmaxf(dec_f32(x0.w) + g0.w, 0.f);
                    av[4] = fmaxf(dec_f32(x1.x) + g1.x, 0.f);
                    av[5] = fmaxf(dec_f32(x1.y) + g1.y, 0.f);
                    av[6] = fmaxf(dec_f32(x1.z) + g1.z, 0.f);
                    av[7] = fmaxf(dec_f32(x1.w) + g1.w, 0.f);
                } else {
                    const float* Ar = (const float*)A_ + (size_t)row * K + 32 * kt + 8 * q;
                    float4 f0 = *(const float4*)Ar;
                    float4 f1 = *(const float4*)(Ar + 4);
                    av[0] = f0.x; av[1] = f0.y; av[2] = f0.z; av[3] = f0.w;
                    av[4] = f1.x; av[5] = f1.y; av[6] = f1.z; av[7] = f1.w;
                }
            }
            uint32x4 t;
            t[0] = cvt_pk_bf16(av[0], av[1]);
            t[1] = cvt_pk_bf16(av[2], av[3]);
            t[2] = cvt_pk_bf16(av[4], av[5]);
            t[3] = cvt_pk_bf16(av[6], av[7]);
            ahi[mt][kt] = __builtin_bit_cast(short8, t);
        }
    }

    f32x4 acc[2][8];
#pragma unroll
    for (int mt = 0; mt < 2; ++mt)
#pragma unroll
        for (int nt = 0; nt < 8; ++nt)
            acc[mt][nt] = (f32x4){0.f, 0.f, 0.f, 0.f};

    const short8* bfr = (const short8*)lds;

    {
        const float4* s4 = (const float4*)Wg;
        float4* d4 = (float4*)lds;
#pragma unroll
        for (int it = 0; it < 2 * KT; ++it) {
            int f = 256 * it + tid;
            int tl = f >> 6, fin = f & 63;
            int tg = (tl >> 3) * 16 + 8 * by + (tl & 7);
            d4[f] = s4[tg * 64 + fin];
        }
    }
    __syncthreads();
#pragma unroll
    for (int nt = 0; nt < 8; ++nt)
#pragma unroll
        for (int kt = 0; kt < KT; ++kt) {
            short8 b = bfr[(kt * 8 + nt) * 64 + l];
            acc[0][nt] = __builtin_amdgcn_mfma_f32_16x16x32_bf16(ahi[0][kt], b, acc[0][nt], 0, 0, 0);
            acc[1][nt] = __builtin_amdgcn_mfma_f32_16x16x32_bf16(ahi[1][kt], b, acc[1][nt], 0, 0, 0);
        }

#pragma unroll
    for (int nt = 0; nt < 8; ++nt) {
        float bias = (by == 0) ? bu[16 * nt + m] : 0.f;
#pragma unroll
        for (int mt = 0; mt < 2; ++mt) {
            int rowb = r0 + 32 * w + 16 * mt + 4 * q;
#pragma unroll
            for (int r = 0; r < 4; ++r) {
                int row = rowb + r;
                if (row < M)
                    C[(size_t)row * 256 + 128 * by + 16 * nt + m] = f2bf(acc[mt][nt][r] + bias);
            }
        }
    }
}

// ---------------- MFMA edge MLP + LDS-table segmented max ----------------
// 128 sorted edges / block, 4 waves, 5 blocks/CU. Run-aware LDS-atomic reduce;
// flush: interior rows plain-store, boundary rows global atomicMax.
__global__ __launch_bounds__(256, 5) void edge_mlp_mfma(
        const unsigned short* __restrict__ UV, // [N][256] bf16: U 0..127 (incl. ba), V 128..255
        const unsigned short* __restrict__ Wg, // hi plane, half-major tiles (16384 shorts)
        const int* __restrict__ ssrc,
        const int* __restrict__ sdst,
        unsigned* __restrict__ AGG) {          // [N][128] encoded (bb added downstream)
    __shared__ char lds[16384 + DMAX * 129 * 4];   // W half | AGGL[DMAX][129]
    unsigned* AGGL = (unsigned*)(lds + 16384);
    int tid = threadIdx.x;
    int orig = blockIdx.x;
    int xcd = orig & 7, ii = orig >> 3;
    int wg = (xcd < XR) ? xcd * (XQ + 1) + ii : XR * (XQ + 1) + (xcd - XR) * XQ + ii;
    int e0 = wg * 128;
    int w = tid >> 6, l = tid & 63;
    int q = l >> 4, m = l & 15;

    int d_lo = sdst[e0], d_hi = sdst[e0 + 127];
    int range = d_hi - d_lo;
    bool fb = range >= DMAX;     // fallback: all-global atomics (rare)

    // gather UV rows (all 16 loads issued up front); each uint = bf16x2
    uint4 ub[2][4], vb[2][4];
    {
        int eA = e0 + 32 * w + m;
        int d0 = sdst[eA], s0 = ssrc[eA];
        int d1 = sdst[eA + 16], s1 = ssrc[eA + 16];
        const uint4* Ud0 = (const uint4*)&UV[(size_t)d0 * 256];
        const uint4* Vs0 = (const uint4*)&UV[(size_t)s0 * 256 + 128];
        const uint4* Ud1 = (const uint4*)&UV[(size_t)d1 * 256];
        const uint4* Vs1 = (const uint4*)&UV[(size_t)s1 * 256 + 128];
#pragma unroll
        for (int kt = 0; kt < 4; ++kt) {
            ub[0][kt] = Ud0[4 * kt + q];
            vb[0][kt] = Vs0[4 * kt + q];
            ub[1][kt] = Ud1[4 * kt + q];
            vb[1][kt] = Vs1[4 * kt + q];
        }
    }

    // dst ids of this lane's 4 reduce rows, per m-tile (D-layout rows 4q+r)
    int4 dd0 = *(const int4*)&sdst[e0 + 32 * w + 4 * q];
    int4 dd1 = *(const int4*)&sdst[e0 + 32 * w + 16 + 4 * q];

    // init AGGL
    if (!fb)
        for (int i = tid; i < DMAX * 129; i += 256) AGGL[i] = ENC_NEG_INF;

    // stage W half 0
    {
        const float4* s4 = (const float4*)Wg;
        float4* d4 = (float4*)lds;
#pragma unroll
        for (int i = 0; i < 4; ++i) d4[tid + 256 * i] = s4[tid + 256 * i];
    }

    // A frags: t = relu(u + v), packed HW converts (v_cvt_pk_bf16_f32)
    short8 ahi[2][4];
#pragma unroll
    for (int mt = 0; mt < 2; ++mt)
#pragma unroll
        for (int kt = 0; kt < 4; ++kt) {
            uint4 u = ub[mt][kt], v = vb[mt][kt];
            uint32x4 t;
            t[0] = pack_relu_add(u.x, v.x);
            t[1] = pack_relu_add(u.y, v.y);
            t[2] = pack_relu_add(u.z, v.z);
            t[3] = pack_relu_add(u.w, v.w);
            ahi[mt][kt] = __builtin_bit_cast(short8, t);
        }

    __syncthreads();   // b1: W half 0 + AGGL init visible

    const short8* bfr = (const short8*)lds;
    f32x4 acc[2][4];

#pragma unroll
    for (int h = 0; h < 2; ++h) {
#pragma unroll
        for (int mt = 0; mt < 2; ++mt)
#pragma unroll
            for (int ntl = 0; ntl < 4; ++ntl)
                acc[mt][ntl] = (f32x4){0.f, 0.f, 0.f, 0.f};
#pragma unroll
        for (int ntl = 0; ntl < 4; ++ntl)
#pragma unroll
            for (int kt = 0; kt < 4; ++kt) {
                short8 b = bfr[(kt * 4 + ntl) * 64 + l];
                acc[0][ntl] = __builtin_amdgcn_mfma_f32_16x16x32_bf16(ahi[0][kt], b, acc[0][ntl], 0, 0, 0);
                acc[1][ntl] = __builtin_amdgcn_mfma_f32_16x16x32_bf16(ahi[1][kt], b, acc[1][ntl], 0, 0, 0);
            }

        if (h == 0) {
            __syncthreads();   // b2: W half 0 readers done
            const float4* s4 = (const float4*)Wg + 1024;
            float4* d4 = (float4*)lds;
#pragma unroll
            for (int i = 0; i < 4; ++i) d4[tid + 256 * i] = s4[tid + 256 * i];
            // W half 1 staging overlaps the reduce below (disjoint LDS regions)
        }

        // run-aware reduce: LDS-table (fast) or global (fallback)
        if (!fb) {
#pragma unroll
            for (int ntl = 0; ntl < 4; ++ntl) {
                int col = 64 * h + 16 * ntl + m;
                segmax4_l(dd0, acc[0][ntl], AGGL, d_lo, col);
                segmax4_l(dd1, acc[1][ntl], AGGL, d_lo, col);
            }
        } else {
#pragma unroll
            for (int ntl = 0; ntl < 4; ++ntl) {
                int col = 64 * h + 16 * ntl + m;
                segmax4_g(dd0, acc[0][ntl], AGG, col);
                segmax4_g(dd1, acc[1][ntl], AGG, col);
            }
        }

        if (h == 0) __syncthreads();   // b3: W half 1 ready
    }

    if (!fb) {
        __syncthreads();   // b4: all LDS atomics done
        // flush: interior rows plain-store (exclusively ours), boundary rows atomic
        int col = tid & 127, rb = tid >> 7;
        for (int r = rb; r <= range; r += 2) {
            unsigned v = AGGL[r * 129 + col];
            int gd = d_lo + r;
            if (r == 0 || r == range) {
                if (v != ENC_NEG_INF) atomicMax(&AGG[(size_t)gd * 128 + col], v);
            } else {
                AGG[(size_t)gd * 128 + col] = v;
            }
        }
    }
}

// ---------------- launch ----------------

extern "C" void kernel_launch(void* const* d_in, const int* in_sizes, int n_in,
                              void* d_out, int out_size, void* d_ws, size_t ws_size,
                              hipStream_t stream) {
    const float* x   = (const float*)d_in[0];
    const int*   ei  = (const int*)d_in[1];
    const float* W1a = (const float*)d_in[2];
    const float* b1a = (const float*)d_in[3];
    const float* W1b = (const float*)d_in[4];
    const float* b1b = (const float*)d_in[5];
    const float* W2a = (const float*)d_in[6];
    const float* b2a = (const float*)d_in[7];
    const float* W2b = (const float*)d_in[8];
    const float* b2b = (const float*)d_in[9];
    const int* src = ei;
    const int* dst = ei + N_EDGES;

    char* ws = (char*)d_ws;
    unsigned short* UV    = (unsigned short*)ws;                 // 25.6 MB (bf16)
    unsigned*       AGG1  = (unsigned*)(ws + 25600000);          // 25.6 MB
    int*            ssrc  = (int*)(ws + 51200000);               // 3.2 MB
    int*            sdst  = (int*)(ws + 54400000);               // 3.2 MB
    unsigned*       count = (unsigned*)(ws + 57600000);          // 200 KB
    unsigned*       cursor= (unsigned*)(ws + 57800000);          // 200 KB
    unsigned short* Wg1   = (unsigned short*)(ws + 58000000);    // 32 KB (W1b hi, half-major)
    unsigned short* Wg2   = (unsigned short*)(ws + 58065536);    // 32 KB (W2b hi)
    unsigned short* WCg1  = (unsigned short*)(ws + 58327680);    // 32 KB (WC1 hi)
    unsigned short* WCg2  = (unsigned short*)(ws + 58393216);    // 64 KB (WC2 hi)
    unsigned*       bsum  = (unsigned*)(ws + 58655744);          // 1 KB

    const int NH = N_NODES * HID;   // 6.4M

    setup<<<2048, 256, 0, stream>>>(W1a, W1b, W2a, W2b, Wg1, Wg2, WCg1, WCg2,
                                    AGG1, (unsigned*)d_out, count);

    // counting sort of edges by dst (max is order-independent -> deterministic)
    hist_dst<<<3125, 256, 0, stream>>>(dst, count);
    scan_p1<<<SCAN_B, 256, 0, stream>>>(count, bsum);
    scan_p2<<<1, 256, 0, stream>>>(bsum);
    scan_p3<<<SCAN_B, 256, 0, stream>>>(count, bsum, cursor);
    scatter_edges<<<3125, 256, 0, stream>>>(src, dst, cursor, ssrc, sdst);

    // Layer 1
    gemm_uv_mfma<0, 2><<<dim3(391, 2), 256, 0, stream>>>(x, WCg1, nullptr, b1a, UV, N_NODES);
    edge_mlp_mfma<<<NWG_E, 256, 0, stream>>>(UV, Wg1, ssrc, sdst, AGG1);

    // Layer 2
    gemm_uv_mfma<1, 4><<<dim3(391, 2), 256, 0, stream>>>(AGG1, WCg2, b1b, b2a, UV, N_NODES);
    edge_mlp_mfma<<<NWG_E, 256, 0, stream>>>(UV, Wg2, ssrc, sdst, (unsigned*)d_out);
    out_decode<<<2048, 256, 0, stream>>>((unsigned*)d_out, b2b, NH);
}

// Round 18
// 279.558 us; speedup vs baseline: 1.1403x; 1.1403x over previous
//
#include <hip/hip_runtime.h>
#include <stdint.h>

#define N_NODES 50000
#define N_EDGES 800000
#define HID 128
#define NWG_E (N_EDGES / 128)      // 6250 edge blocks
#define XQ (NWG_E / 8)             // 781
#define XR (NWG_E % 8)             // 2
#define SCAN_B 196                 // 196*256 = 50176 >= N_NODES
#define DMAX 40                    // max dst-range per block for LDS-table path

#define ENC_NEG_INF 0x007FFFFFu   // enc(-inf)

typedef short short8 __attribute__((ext_vector_type(8)));
typedef float f32x4 __attribute__((ext_vector_type(4)));
typedef unsigned int uint32x4 __attribute__((ext_vector_type(4)));

__device__ __forceinline__ unsigned enc_f32(float f) {
    unsigned u = __float_as_uint(f);
    return (u & 0x80000000u) ? ~u : (u | 0x80000000u);
}
__device__ __forceinline__ float dec_f32(unsigned e) {
    unsigned u = (e & 0x80000000u) ? (e & 0x7FFFFFFFu) : ~e;
    return __uint_as_float(u);
}
__device__ __forceinline__ unsigned short f2bf(float f) {   // RNE bit-trick
    unsigned u = __float_as_uint(f);
    unsigned r = (u + 0x7fffu + ((u >> 16) & 1u)) >> 16;
    return (unsigned short)r;
}
__device__ __forceinline__ float bf2f(unsigned short h) {
    return __uint_as_float(((unsigned)h) << 16);
}
// HW packed convert: 2 f32 -> bf16x2 word (RNE, v_cvt_pk_bf16_f32)
__device__ __forceinline__ unsigned cvt_pk_bf16(float lo, float hi) {
    unsigned r;
    asm("v_cvt_pk_bf16_f32 %0, %1, %2" : "=v"(r) : "v"(lo), "v"(hi));
    return r;
}
// t = relu(u + v) on a bf16x2 word, packed
__device__ __forceinline__ unsigned pack_relu_add(unsigned uu, unsigned vv) {
    float s0 = __uint_as_float(uu << 16) + __uint_as_float(vv << 16);
    float s1 = __uint_as_float(uu & 0xffff0000u) + __uint_as_float(vv & 0xffff0000u);
    return cvt_pk_bf16(fmaxf(s0, 0.f), fmaxf(s1, 0.f));
}
__device__ __forceinline__ float wcat_val(const float* __restrict__ W, int K, int k, int n) {
    return (n < 128) ? (W[k * 128 + n] - W[(k + K) * 128 + n]) : W[(k + K) * 128 + (n - 128)];
}

// run-aware reduce over 4 sorted edges -> LDS table (fast path).
// Common case (all 4 same dst): 1 compare + 1 atomic. Else: 4 plain atomics.
__device__ __forceinline__ void segmax4_l(int4 dd, f32x4 v, unsigned* AGGL, int dlo, int col) {
    if (dd.x == dd.w) {
        float mx = fmaxf(fmaxf(v[0], v[1]), fmaxf(v[2], v[3]));
        atomicMax(&AGGL[(dd.x - dlo) * 129 + col], enc_f32(mx));
    } else {
        atomicMax(&AGGL[(dd.x - dlo) * 129 + col], enc_f32(v[0]));
        atomicMax(&AGGL[(dd.y - dlo) * 129 + col], enc_f32(v[1]));
        atomicMax(&AGGL[(dd.z - dlo) * 129 + col], enc_f32(v[2]));
        atomicMax(&AGGL[(dd.w - dlo) * 129 + col], enc_f32(v[3]));
    }
}
// fallback: global atomics (rare; block-uniform)
__device__ __forceinline__ void segmax4_g(int4 dd, f32x4 v, unsigned* __restrict__ AGG, int col) {
    if (dd.x == dd.w) {
        float mx = fmaxf(fmaxf(v[0], v[1]), fmaxf(v[2], v[3]));
        atomicMax(&AGG[(size_t)dd.x * 128 + col], enc_f32(mx));
    } else {
        atomicMax(&AGG[(size_t)dd.x * 128 + col], enc_f32(v[0]));
        atomicMax(&AGG[(size_t)dd.y * 128 + col], enc_f32(v[1]));
        atomicMax(&AGG[(size_t)dd.z * 128 + col], enc_f32(v[2]));
        atomicMax(&AGG[(size_t)dd.w * 128 + col], enc_f32(v[3]));
    }
}

// ---------------- fused setup: W-frag preps (hi planes only) + big fills ----------------
__global__ __launch_bounds__(256) void setup(
        const float* __restrict__ W1a, const float* __restrict__ W1b,
        const float* __restrict__ W2a, const float* __restrict__ W2b,
        unsigned short* __restrict__ Wg1, unsigned short* __restrict__ Wg2,
        unsigned short* __restrict__ WCg1, unsigned short* __restrict__ WCg2,
        unsigned* __restrict__ AGG1, unsigned* __restrict__ OUT,
        unsigned* __restrict__ count) {
    int bid = blockIdx.x, tid = threadIdx.x;
    const int NH = N_NODES * HID;

    if (bid < 128) {
        const float* Wb = (bid < 64) ? W1b : W2b;
        unsigned short* Wg = (bid < 64) ? Wg1 : Wg2;
        int idx = (bid & 63) * 256 + tid;
        int j = idx & 7, l = (idx >> 3) & 63, t = idx >> 9;
        int h = t >> 4, kt = (t >> 2) & 3, ntl = t & 3;
        int nt = 4 * h + ntl;
        int k = 32 * kt + 8 * (l >> 4) + j;
        int n = 16 * nt + (l & 15);
        Wg[idx] = f2bf(Wb[k * 128 + n]);
    } else if (bid < 192) {
        int idx = (bid - 128) * 256 + tid;
        int j = idx & 7, l = (idx >> 3) & 63, nt = (idx >> 9) & 15, kt = idx >> 13;
        int k = 32 * kt + 8 * (l >> 4) + j;
        int n = 16 * nt + (l & 15);
        WCg1[idx] = f2bf(wcat_val(W1a, 64, k, n));
    } else if (bid < 320) {
        int idx = (bid - 192) * 256 + tid;
        int j = idx & 7, l = (idx >> 3) & 63, nt = (idx >> 9) & 15, kt = idx >> 13;
        int k = 32 * kt + 8 * (l >> 4) + j;
        int n = 16 * nt + (l & 15);
        WCg2[idx] = f2bf(wcat_val(W2a, 128, k, n));
    }

    int total = 2 * NH + N_NODES;
    for (int i = bid * 256 + tid; i < total; i += gridDim.x * 256) {
        if (i < NH) AGG1[i] = ENC_NEG_INF;
        else if (i < 2 * NH) OUT[i - NH] = ENC_NEG_INF;
        else count[i - 2 * NH] = 0u;
    }
}

__global__ void out_decode(unsigned* __restrict__ p, const float* __restrict__ bias, int n) {
    int i = blockIdx.x * blockDim.x + threadIdx.x;
    int stride = gridDim.x * blockDim.x;
    for (; i < n; i += stride) {
        unsigned e = p[i];
        float f = (e == ENC_NEG_INF) ? 0.0f : dec_f32(e) + bias[i & 127];
        ((float*)p)[i] = f;
    }
}

// ---------------- sort-by-dst (counting sort, multi-block scan) ----------------

__global__ void hist_dst(const int* __restrict__ dst, unsigned* __restrict__ count) {
    int i = blockIdx.x * blockDim.x + threadIdx.x;
    if (i < N_EDGES) atomicAdd(&count[dst[i]], 1u);
}

__global__ __launch_bounds__(256) void scan_p1(const unsigned* __restrict__ count,
                                               unsigned* __restrict__ bsum) {
    __shared__ unsigned s[256];
    int t = threadIdx.x;
    int i = blockIdx.x * 256 + t;
    s[t] = (i < N_NODES) ? count[i] : 0u;
    __syncthreads();
    for (int off = 128; off > 0; off >>= 1) {
        if (t < off) s[t] += s[t + off];
        __syncthreads();
    }
    if (t == 0) bsum[blockIdx.x] = s[0];
}

__global__ __launch_bounds__(256) void scan_p2(unsigned* __restrict__ bsum) {
    __shared__ unsigned s[256];
    int t = threadIdx.x;
    unsigned v = (t < SCAN_B) ? bsum[t] : 0u;
    s[t] = v;
    __syncthreads();
    for (int off = 1; off < 256; off <<= 1) {
        unsigned x = (t >= off) ? s[t - off] : 0u;
        __syncthreads();
        s[t] += x;
        __syncthreads();
    }
    if (t < SCAN_B) bsum[t] = s[t] - v;   // exclusive
}

__global__ __launch_bounds__(256) void scan_p3(const unsigned* __restrict__ count,
                                               const unsigned* __restrict__ bsum,
                                               unsigned* __restrict__ cursor) {
    __shared__ unsigned s[256];
    int t = threadIdx.x;
    int i = blockIdx.x * 256 + t;
    unsigned v = (i < N_NODES) ? count[i] : 0u;
    s[t] = v;
    __syncthreads();
    for (int off = 1; off < 256; off <<= 1) {
        unsigned x = (t >= off) ? s[t - off] : 0u;
        __syncthreads();
        s[t] += x;
        __syncthreads();
    }
    if (i < N_NODES) cursor[i] = bsum[blockIdx.x] + s[t] - v;
}

__global__ void scatter_edges(const int* __restrict__ src, const int* __restrict__ dst,
                              unsigned* __restrict__ cursor,
                              int* __restrict__ ssrc, int* __restrict__ sdst) {
    int i = blockIdx.x * blockDim.x + threadIdx.x;
    if (i < N_EDGES) {
        int d = dst[i];
        unsigned p = atomicAdd(&cursor[d], 1u);
        ssrc[p] = src[i];
        sdst[p] = d;
    }
}

// ---------------- MFMA node GEMM: C[M][256](bf16) = op(A)[M][K] @ WC_hi[K][256] ----------------
template<int DEC, int KT>
__global__ __launch_bounds__(256, 3) void gemm_uv_mfma(
        const void* __restrict__ A_,
        const unsigned short* __restrict__ Wg,
        const float* __restrict__ bprev,
        const float* __restrict__ bu,
        unsigned short* __restrict__ C,
        int M) {
    __shared__ char lds[KT * 8192];
    const int K = 32 * KT;
    int tid = threadIdx.x;
    int bx = blockIdx.x, by = blockIdx.y;
    int r0 = bx * 128;
    int w = tid >> 6, l = tid & 63;
    int q = l >> 4, m = l & 15;

    short8 ahi[2][KT];
#pragma unroll
    for (int mt = 0; mt < 2; ++mt) {
        int row = r0 + 32 * w + 16 * mt + m;
        bool ok = row < M;
#pragma unroll
        for (int kt = 0; kt < KT; ++kt) {
            float av[8] = {0.f, 0.f, 0.f, 0.f, 0.f, 0.f, 0.f, 0.f};
            if (ok) {
                if (DEC) {
                    const unsigned* Ar = (const unsigned*)A_ + (size_t)row * K + 32 * kt + 8 * q;
                    uint4 x0 = *(const uint4*)Ar;
                    uint4 x1 = *(const uint4*)(Ar + 4);
                    float4 g0 = *(const float4*)&bprev[32 * kt + 8 * q];
                    float4 g1 = *(const float4*)&bprev[32 * kt + 8 * q + 4];
                    av[0] = fmaxf(dec_f32(x0.x) + g0.x, 0.f);
                    av[1] = fmaxf(dec_f32(x0.y) + g0.y, 0.f);
                    av[2] = fmaxf(dec_f32(x0.z) + g0.z, 0.f);
                    av[3] = fmaxf(dec_f32(x0.w) + g0.w, 0.f);
                    av[4] = fmaxf(dec_f32(x1.x) + g1.x, 0.f);
                    av[5] = fmaxf(dec_f32(x1.y) + g1.y, 0.f);
                    av[6] = fmaxf(dec_f32(x1.z) + g1.z, 0.f);
                    av[7] = fmaxf(dec_f32(x1.w) + g1.w, 0.f);
                } else {
                    const float* Ar = (const float*)A_ + (size_t)row * K + 32 * kt + 8 * q;
                    float4 f0 = *(const float4*)Ar;
                    float4 f1 = *(const float4*)(Ar + 4);
                    av[0] = f0.x; av[1] = f0.y; av[2] = f0.z; av[3] = f0.w;
                    av[4] = f1.x; av[5] = f1.y; av[6] = f1.z; av[7] = f1.w;
                }
            }
            uint32x4 t;
            t[0] = cvt_pk_bf16(av[0], av[1]);
            t[1] = cvt_pk_bf16(av[2], av[3]);
            t[2] = cvt_pk_bf16(av[4], av[5]);
            t[3] = cvt_pk_bf16(av[6], av[7]);
            ahi[mt][kt] = __builtin_bit_cast(short8, t);
        }
    }

    f32x4 acc[2][8];
#pragma unroll
    for (int mt = 0; mt < 2; ++mt)
#pragma unroll
        for (int nt = 0; nt < 8; ++nt)
            acc[mt][nt] = (f32x4){0.f, 0.f, 0.f, 0.f};

    const short8* bfr = (const short8*)lds;

    {
        const float4* s4 = (const float4*)Wg;
        float4* d4 = (float4*)lds;
#pragma unroll
        for (int it = 0; it < 2 * KT; ++it) {
            int f = 256 * it + tid;
            int tl = f >> 6, fin = f & 63;
            int tg = (tl >> 3) * 16 + 8 * by + (tl & 7);
            d4[f] = s4[tg * 64 + fin];
        }
    }
    __syncthreads();
#pragma unroll
    for (int nt = 0; nt < 8; ++nt)
#pragma unroll
        for (int kt = 0; kt < KT; ++kt) {
            short8 b = bfr[(kt * 8 + nt) * 64 + l];
            acc[0][nt] = __builtin_amdgcn_mfma_f32_16x16x32_bf16(ahi[0][kt], b, acc[0][nt], 0, 0, 0);
            acc[1][nt] = __builtin_amdgcn_mfma_f32_16x16x32_bf16(ahi[1][kt], b, acc[1][nt], 0, 0, 0);
        }

#pragma unroll
    for (int nt = 0; nt < 8; ++nt) {
        float bias = (by == 0) ? bu[16 * nt + m] : 0.f;
#pragma unroll
        for (int mt = 0; mt < 2; ++mt) {
            int rowb = r0 + 32 * w + 16 * mt + 4 * q;
#pragma unroll
            for (int r = 0; r < 4; ++r) {
                int row = rowb + r;
                if (row < M)
                    C[(size_t)row * 256 + 128 * by + 16 * nt + m] = f2bf(acc[mt][nt][r] + bias);
            }
        }
    }
}

// ---------------- MFMA edge MLP + LDS-table segmented max ----------------
// 128 sorted edges / block, 4 waves, 4 blocks/CU. Run-aware LDS-atomic reduce;
// flush: interior rows plain-store, boundary rows global atomicMax.
__global__ __launch_bounds__(256, 4) void edge_mlp_mfma(
        const unsigned short* __restrict__ UV, // [N][256] bf16: U 0..127 (incl. ba), V 128..255
        const unsigned short* __restrict__ Wg, // hi plane, half-major tiles (16384 shorts)
        const int* __restrict__ ssrc,
        const int* __restrict__ sdst,
        unsigned* __restrict__ AGG) {          // [N][128] encoded (bb added downstream)
    __shared__ char lds[16384 + DMAX * 129 * 4];   // W half | AGGL[DMAX][129]
    unsigned* AGGL = (unsigned*)(lds + 16384);
    int tid = threadIdx.x;
    int orig = blockIdx.x;
    int xcd = orig & 7, ii = orig >> 3;
    int wg = (xcd < XR) ? xcd * (XQ + 1) + ii : XR * (XQ + 1) + (xcd - XR) * XQ + ii;
    int e0 = wg * 128;
    int w = tid >> 6, l = tid & 63;
    int q = l >> 4, m = l & 15;

    int d_lo = sdst[e0], d_hi = sdst[e0 + 127];
    int range = d_hi - d_lo;
    bool fb = range >= DMAX;     // fallback: all-global atomics (rare)

    // gather UV rows (all 16 loads issued up front); each uint = bf16x2
    uint4 ub[2][4], vb[2][4];
    {
        int eA = e0 + 32 * w + m;
        int d0 = sdst[eA], s0 = ssrc[eA];
        int d1 = sdst[eA + 16], s1 = ssrc[eA + 16];
        const uint4* Ud0 = (const uint4*)&UV[(size_t)d0 * 256];
        const uint4* Vs0 = (const uint4*)&UV[(size_t)s0 * 256 + 128];
        const uint4* Ud1 = (const uint4*)&UV[(size_t)d1 * 256];
        const uint4* Vs1 = (const uint4*)&UV[(size_t)s1 * 256 + 128];
#pragma unroll
        for (int kt = 0; kt < 4; ++kt) {
            ub[0][kt] = Ud0[4 * kt + q];
            vb[0][kt] = Vs0[4 * kt + q];
            ub[1][kt] = Ud1[4 * kt + q];
            vb[1][kt] = Vs1[4 * kt + q];
        }
    }

    // dst ids of this lane's 4 reduce rows, per m-tile (D-layout rows 4q+r)
    int4 dd0 = *(const int4*)&sdst[e0 + 32 * w + 4 * q];
    int4 dd1 = *(const int4*)&sdst[e0 + 32 * w + 16 + 4 * q];

    // init AGGL
    if (!fb)
        for (int i = tid; i < DMAX * 129; i += 256) AGGL[i] = ENC_NEG_INF;

    // stage W half 0
    {
        const float4* s4 = (const float4*)Wg;
        float4* d4 = (float4*)lds;
#pragma unroll
        for (int i = 0; i < 4; ++i) d4[tid + 256 * i] = s4[tid + 256 * i];
    }

    // A frags: t = relu(u + v), packed HW converts (v_cvt_pk_bf16_f32)
    short8 ahi[2][4];
#pragma unroll
    for (int mt = 0; mt < 2; ++mt)
#pragma unroll
        for (int kt = 0; kt < 4; ++kt) {
            uint4 u = ub[mt][kt], v = vb[mt][kt];
            uint32x4 t;
            t[0] = pack_relu_add(u.x, v.x);
            t[1] = pack_relu_add(u.y, v.y);
            t[2] = pack_relu_add(u.z, v.z);
            t[3] = pack_relu_add(u.w, v.w);
            ahi[mt][kt] = __builtin_bit_cast(short8, t);
        }

    __syncthreads();   // b1: W half 0 + AGGL init visible

    const short8* bfr = (const short8*)lds;
    f32x4 acc[2][4];

#pragma unroll
    for (int h = 0; h < 2; ++h) {
#pragma unroll
        for (int mt = 0; mt < 2; ++mt)
#pragma unroll
            for (int ntl = 0; ntl < 4; ++ntl)
                acc[mt][ntl] = (f32x4){0.f, 0.f, 0.f, 0.f};
#pragma unroll
        for (int ntl = 0; ntl < 4; ++ntl)
#pragma unroll
            for (int kt = 0; kt < 4; ++kt) {
                short8 b = bfr[(kt * 4 + ntl) * 64 + l];
                acc[0][ntl] = __builtin_amdgcn_mfma_f32_16x16x32_bf16(ahi[0][kt], b, acc[0][ntl], 0, 0, 0);
                acc[1][ntl] = __builtin_amdgcn_mfma_f32_16x16x32_bf16(ahi[1][kt], b, acc[1][ntl], 0, 0, 0);
            }

        if (h == 0) {
            __syncthreads();   // b2: W half 0 readers done
            const float4* s4 = (const float4*)Wg + 1024;
            float4* d4 = (float4*)lds;
#pragma unroll
            for (int i = 0; i < 4; ++i) d4[tid + 256 * i] = s4[tid + 256 * i];
            // W half 1 staging overlaps the reduce below (disjoint LDS regions)
        }

        // run-aware reduce: LDS-table (fast) or global (fallback)
        if (!fb) {
#pragma unroll
            for (int ntl = 0; ntl < 4; ++ntl) {
                int col = 64 * h + 16 * ntl + m;
                segmax4_l(dd0, acc[0][ntl], AGGL, d_lo, col);
                segmax4_l(dd1, acc[1][ntl], AGGL, d_lo, col);
            }
        } else {
#pragma unroll
            for (int ntl = 0; ntl < 4; ++ntl) {
                int col = 64 * h + 16 * ntl + m;
                segmax4_g(dd0, acc[0][ntl], AGG, col);
                segmax4_g(dd1, acc[1][ntl], AGG, col);
            }
        }

        if (h == 0) __syncthreads();   // b3: W half 1 ready
    }

    if (!fb) {
        __syncthreads();   // b4: all LDS atomics done
        // flush: interior rows plain-store (exclusively ours), boundary rows atomic
        int col = tid & 127, rb = tid >> 7;
        for (int r = rb; r <= range; r += 2) {
            unsigned v = AGGL[r * 129 + col];
            int gd = d_lo + r;
            if (r == 0 || r == range) {
                if (v != ENC_NEG_INF) atomicMax(&AGG[(size_t)gd * 128 + col], v);
            } else {
                AGG[(size_t)gd * 128 + col] = v;
            }
        }
    }
}

// ---------------- launch ----------------

extern "C" void kernel_launch(void* const* d_in, const int* in_sizes, int n_in,
                              void* d_out, int out_size, void* d_ws, size_t ws_size,
                              hipStream_t stream) {
    const float* x   = (const float*)d_in[0];
    const int*   ei  = (const int*)d_in[1];
    const float* W1a = (const float*)d_in[2];
    const float* b1a = (const float*)d_in[3];
    const float* W1b = (const float*)d_in[4];
    const float* b1b = (const float*)d_in[5];
    const float* W2a = (const float*)d_in[6];
    const float* b2a = (const float*)d_in[7];
    const float* W2b = (const float*)d_in[8];
    const float* b2b = (const float*)d_in[9];
    const int* src = ei;
    const int* dst = ei + N_EDGES;

    char* ws = (char*)d_ws;
    unsigned short* UV    = (unsigned short*)ws;                 // 25.6 MB (bf16)
    unsigned*       AGG1  = (unsigned*)(ws + 25600000);          // 25.6 MB
    int*            ssrc  = (int*)(ws + 51200000);               // 3.2 MB
    int*            sdst  = (int*)(ws + 54400000);               // 3.2 MB
    unsigned*       count = (unsigned*)(ws + 57600000);          // 200 KB
    unsigned*       cursor= (unsigned*)(ws + 57800000);          // 200 KB
    unsigned short* Wg1   = (unsigned short*)(ws + 58000000);    // 32 KB (W1b hi, half-major)
    unsigned short* Wg2   = (unsigned short*)(ws + 58065536);    // 32 KB (W2b hi)
    unsigned short* WCg1  = (unsigned short*)(ws + 58327680);    // 32 KB (WC1 hi)
    unsigned short* WCg2  = (unsigned short*)(ws + 58393216);    // 64 KB (WC2 hi)
    unsigned*       bsum  = (unsigned*)(ws + 58655744);          // 1 KB

    const int NH = N_NODES * HID;   // 6.4M

    setup<<<2048, 256, 0, stream>>>(W1a, W1b, W2a, W2b, Wg1, Wg2, WCg1, WCg2,
                                    AGG1, (unsigned*)d_out, count);

    // counting sort of edges by dst (max is order-independent -> deterministic)
    hist_dst<<<3125, 256, 0, stream>>>(dst, count);
    scan_p1<<<SCAN_B, 256, 0, stream>>>(count, bsum);
    scan_p2<<<1, 256, 0, stream>>>(bsum);
    scan_p3<<<SCAN_B, 256, 0, stream>>>(count, bsum, cursor);
    scatter_edges<<<3125, 256, 0, stream>>>(src, dst, cursor, ssrc, sdst);

    // Layer 1
    gemm_uv_mfma<0, 2><<<dim3(391, 2), 256, 0, stream>>>(x, WCg1, nullptr, b1a, UV, N_NODES);
    edge_mlp_mfma<<<NWG_E, 256, 0, stream>>>(UV, Wg1, ssrc, sdst, AGG1);

    // Layer 2
    gemm_uv_mfma<1, 4><<<dim3(391, 2), 256, 0, stream>>>(AGG1, WCg2, b1b, b2a, UV, N_NODES);
    edge_mlp_mfma<<<NWG_E, 256, 0, stream>>>(UV, Wg2, ssrc, sdst, (unsigned*)d_out);
    out_decode<<<2048, 256, 0, stream>>>((unsigned*)d_out, b2b, NH);
}